// Round 2
// baseline (329.258 us; speedup 1.0000x reference)
//
#include <hip/hip_runtime.h>

typedef unsigned short ushort_t;
using bf16x8 = __attribute__((ext_vector_type(8))) short;
using f32x4  = __attribute__((ext_vector_type(4))) float;

#define N_VOX 65536
#define KT 27
#define CH 64

__device__ inline unsigned short f2bf(float f) {
  unsigned int u = __builtin_bit_cast(unsigned int, f);
  u += 0x7fffu + ((u >> 16) & 1u);
  return (unsigned short)(u >> 16);
}

// ---- merged prep: x fp32->bf16 (4096 blocks), W1 and W2 [k][c][d] -> bf16 [k][d][c] (432 blocks each) ----
__global__ __launch_bounds__(256) void k_prep(const float* __restrict__ x,
                                              const float* __restrict__ W1,
                                              const float* __restrict__ W2,
                                              ushort_t* __restrict__ xb,
                                              ushort_t* __restrict__ W1t,
                                              ushort_t* __restrict__ W2t) {
  int b = blockIdx.x;
  int t = threadIdx.x;
  if (b < 4096) {
    int i = b * 256 + t;  // float4 index, N*CH/4 total
    float4 v = ((const float4*)x)[i];
    ushort4 o;
    o.x = f2bf(v.x); o.y = f2bf(v.y); o.z = f2bf(v.z); o.w = f2bf(v.w);
    ((ushort4*)xb)[i] = o;
  } else {
    const float* W = (b < 4528) ? W1 : W2;
    ushort_t* Wt = (b < 4528) ? W1t : W2t;
    int e = ((b < 4528) ? (b - 4096) : (b - 4528)) * 256 + t;  // < 27*4096
    int k = e >> 12;
    int rem = e & 4095;
    int d = rem >> 6;
    int c = rem & 63;
    Wt[e] = f2bf(W[(k << 12) + (c << 6) + d]);
  }
}

// ---- gather-GEMM conv via MFMA, zero LDS tiling, register-direct fragments ----
// block = 256 thr = 4 independent waves; wave w owns voxels base+w*16..+15, all 64 out channels.
// A frag: lane(m,quad) = xb[idx(m)*64 + quad*8 (+32)]  -- direct 16B gather, masked taps skipped.
// B frag: lane(m,quad) = Wt[k][nt*16+m][quad*8 (+32)]  -- direct 16B, W L1/L2-resident.
// 1-deep register prefetch (double buffer), no per-tap barriers, fused per-channel stats.
__global__ __launch_bounds__(256, 4) void k_conv(const ushort_t* __restrict__ xb,   // [N][64] bf16
                                                 const int* __restrict__ nbr,      // [N][27]
                                                 const ushort_t* __restrict__ Wt,  // [27][64(d)][64(c)] bf16
                                                 float* __restrict__ hout,         // [N][64] fp32
                                                 float* __restrict__ gsum,         // [64]
                                                 float* __restrict__ gsq) {        // [64]
  __shared__ int nb_l[64 * KT];        // [voxel][tap]
  __shared__ float red[2][4][64];      // [sum|sq][wave][channel]
  const int t = threadIdx.x;
  const int base = blockIdx.x * 64;

  // stage this block's rulebook rows (coalesced; [v][k] layout -> conflict-free reads)
  for (int e = t; e < 64 * KT; e += 256) nb_l[e] = nbr[base * KT + e];

  const int lane = t & 63;
  const int w = t >> 6;
  const int m = lane & 15;
  const int quad = lane >> 4;

  const int* myNb = nb_l + (w * 16 + m) * KT;
  const ushort_t* aBase = xb + quad * 8;            // + idx*64; +32 for K-step 1
  const ushort_t* bBase = Wt + m * 64 + quad * 8;   // + k*4096 + nt*1024; +32 for K-step 1

  f32x4 acc[4] = {{0.f,0.f,0.f,0.f},{0.f,0.f,0.f,0.f},{0.f,0.f,0.f,0.f},{0.f,0.f,0.f,0.f}};

  __syncthreads();  // nb_l ready

  bf16x8 a0b[2], a1b[2];
  bf16x8 b0b[2][4], b1b[2][4];

  // prefetch tap 0 into buffer 0
  {
    bf16x8 z = {0,0,0,0,0,0,0,0};
    a0b[0] = z; a1b[0] = z;
    int idx = myNb[0];
    if (idx >= 0) {
      const ushort_t* p = aBase + idx * 64;
      a0b[0] = *(const bf16x8*)p;
      a1b[0] = *(const bf16x8*)(p + 32);
    }
#pragma unroll
    for (int nt = 0; nt < 4; ++nt) {
      const ushort_t* p = bBase + nt * 1024;
      b0b[0][nt] = *(const bf16x8*)p;
      b1b[0][nt] = *(const bf16x8*)(p + 32);
    }
  }

#pragma unroll 2
  for (int k = 0; k < KT - 1; ++k) {
    const int cur = k & 1, nxt = (k + 1) & 1;
    // prefetch tap k+1
    {
      bf16x8 z = {0,0,0,0,0,0,0,0};
      a0b[nxt] = z; a1b[nxt] = z;
      int idx = myNb[k + 1];
      if (idx >= 0) {
        const ushort_t* p = aBase + idx * 64;
        a0b[nxt] = *(const bf16x8*)p;
        a1b[nxt] = *(const bf16x8*)(p + 32);
      }
      const ushort_t* wn = bBase + (k + 1) * 4096;
#pragma unroll
      for (int nt = 0; nt < 4; ++nt) {
        const ushort_t* p = wn + nt * 1024;
        b0b[nxt][nt] = *(const bf16x8*)p;
        b1b[nxt][nt] = *(const bf16x8*)(p + 32);
      }
    }
    // compute tap k
#pragma unroll
    for (int nt = 0; nt < 4; ++nt) {
      acc[nt] = __builtin_amdgcn_mfma_f32_16x16x32_bf16(a0b[cur], b0b[cur][nt], acc[nt], 0, 0, 0);
      acc[nt] = __builtin_amdgcn_mfma_f32_16x16x32_bf16(a1b[cur], b1b[cur][nt], acc[nt], 0, 0, 0);
    }
  }
  // final tap (in buffer (KT-1)&1 == 0)
#pragma unroll
  for (int nt = 0; nt < 4; ++nt) {
    acc[nt] = __builtin_amdgcn_mfma_f32_16x16x32_bf16(a0b[0], b0b[0][nt], acc[nt], 0, 0, 0);
    acc[nt] = __builtin_amdgcn_mfma_f32_16x16x32_bf16(a1b[0], b1b[0][nt], acc[nt], 0, 0, 0);
  }

  // epilogue: store h + fused per-channel stats
  // C/D layout: col = lane&15, row = quad*4 + reg
  const int orow = base + w * 16 + quad * 4;
  float s[4], q[4];
#pragma unroll
  for (int nt = 0; nt < 4; ++nt) {
    float ss = 0.f, qq = 0.f;
#pragma unroll
    for (int r = 0; r < 4; ++r) {
      float v = acc[nt][r];
      hout[(orow + r) * 64 + nt * 16 + m] = v;
      ss += v; qq += v * v;
    }
    s[nt] = ss; q[nt] = qq;
  }
#pragma unroll
  for (int nt = 0; nt < 4; ++nt) {
    s[nt] += __shfl_xor(s[nt], 16, 64); s[nt] += __shfl_xor(s[nt], 32, 64);
    q[nt] += __shfl_xor(q[nt], 16, 64); q[nt] += __shfl_xor(q[nt], 32, 64);
  }
  if (quad == 0) {
#pragma unroll
    for (int nt = 0; nt < 4; ++nt) {
      red[0][w][nt * 16 + m] = s[nt];
      red[1][w][nt * 16 + m] = q[nt];
    }
  }
  __syncthreads();
  if (t < 128) {
    int which = t >> 6, c = t & 63;
    float v = red[which][0][c] + red[which][1][c] + red[which][2][c] + red[which][3][c];
    atomicAdd((which ? gsq : gsum) + c, v);
  }
}

// ---- BN1 (params computed inline from raw stats) + ReLU + cast to bf16 ----
__global__ __launch_bounds__(256) void k_bn_relu(const float* __restrict__ h,
                                                 const float* __restrict__ gsum,
                                                 const float* __restrict__ gsq,
                                                 const float* __restrict__ gamma,
                                                 const float* __restrict__ beta,
                                                 ushort_t* __restrict__ ob) {
  __shared__ float sc[64], sh[64];
  int t = threadIdx.x;
  if (t < 64) {
    float mean = gsum[t] * (1.f / N_VOX);
    float var = gsq[t] * (1.f / N_VOX) - mean * mean;
    float rs = rsqrtf(var + 1e-5f);
    float s = gamma[t] * rs;
    sc[t] = s;
    sh[t] = beta[t] - mean * s;
  }
  __syncthreads();
  int i = blockIdx.x * 256 + t;  // float4 index
  int c0 = (i << 2) & 63;
  float4 v = ((const float4*)h)[i];
  ushort4 o;
  o.x = f2bf(fmaxf(0.f, v.x * sc[c0]     + sh[c0]));
  o.y = f2bf(fmaxf(0.f, v.y * sc[c0 + 1] + sh[c0 + 1]));
  o.z = f2bf(fmaxf(0.f, v.z * sc[c0 + 2] + sh[c0 + 2]));
  o.w = f2bf(fmaxf(0.f, v.w * sc[c0 + 3] + sh[c0 + 3]));
  ((ushort4*)ob)[i] = o;
}

// ---- BN2 (inline params) + residual + ReLU, fp32 out ----
__global__ __launch_bounds__(256) void k_final(const float* __restrict__ h,
                                               const float* __restrict__ x,
                                               const float* __restrict__ gsum,
                                               const float* __restrict__ gsq,
                                               const float* __restrict__ gamma,
                                               const float* __restrict__ beta,
                                               float* __restrict__ out) {
  __shared__ float sc[64], sh[64];
  int t = threadIdx.x;
  if (t < 64) {
    float mean = gsum[t] * (1.f / N_VOX);
    float var = gsq[t] * (1.f / N_VOX) - mean * mean;
    float rs = rsqrtf(var + 1e-5f);
    float s = gamma[t] * rs;
    sc[t] = s;
    sh[t] = beta[t] - mean * s;
  }
  __syncthreads();
  int i = blockIdx.x * 256 + t;
  int c0 = (i << 2) & 63;
  float4 v = ((const float4*)h)[i];
  float4 xv = ((const float4*)x)[i];
  float4 o;
  o.x = fmaxf(0.f, v.x * sc[c0]     + sh[c0]     + xv.x);
  o.y = fmaxf(0.f, v.y * sc[c0 + 1] + sh[c0 + 1] + xv.y);
  o.z = fmaxf(0.f, v.z * sc[c0 + 2] + sh[c0 + 2] + xv.z);
  o.w = fmaxf(0.f, v.w * sc[c0 + 3] + sh[c0 + 3] + xv.w);
  ((float4*)out)[i] = o;
}

extern "C" void kernel_launch(void* const* d_in, const int* in_sizes, int n_in,
                              void* d_out, int out_size, void* d_ws, size_t ws_size,
                              hipStream_t stream) {
  const float* x   = (const float*)d_in[0];
  const int*   nbr = (const int*)d_in[1];
  const float* W1  = (const float*)d_in[2];
  const float* g1  = (const float*)d_in[3];
  const float* b1  = (const float*)d_in[4];
  const float* W2  = (const float*)d_in[5];
  const float* g2  = (const float*)d_in[6];
  const float* b2  = (const float*)d_in[7];
  float* out = (float*)d_out;
  char* ws = (char*)d_ws;

  // workspace layout (bytes), all 256-aligned; total ~50.8 MB
  ushort_t* xb    = (ushort_t*)(ws);               // 8,388,608
  ushort_t* h1b   = (ushort_t*)(ws + 8388608);     // 8,388,608
  ushort_t* W1t   = (ushort_t*)(ws + 16777216);    // 221,184
  ushort_t* W2t   = (ushort_t*)(ws + 16998400);    // 221,184
  float*    h1raw = (float*)(ws + 17219584);       // 16,777,216
  float*    h2raw = (float*)(ws + 33996800);       // 16,777,216
  float*    statsp  = (float*)(ws + 50774016);     // 4 x 64 floats
  float *gsum1 = statsp, *gsq1 = statsp + 64, *gsum2 = statsp + 128, *gsq2 = statsp + 192;

  hipMemsetAsync(statsp, 0, 256 * sizeof(float), stream);

  k_prep<<<4960, 256, 0, stream>>>(x, W1, W2, xb, W1t, W2t);

  k_conv<<<1024, 256, 0, stream>>>(xb, nbr, W1t, h1raw, gsum1, gsq1);
  k_bn_relu<<<4096, 256, 0, stream>>>(h1raw, gsum1, gsq1, g1, b1, h1b);

  k_conv<<<1024, 256, 0, stream>>>(h1b, nbr, W2t, h2raw, gsum2, gsq2);
  k_final<<<4096, 256, 0, stream>>>(h2raw, x, gsum2, gsq2, g2, b2, out);
}

// Round 3
// 233.930 us; speedup vs baseline: 1.4075x; 1.4075x over previous
//
#include <hip/hip_runtime.h>

typedef unsigned short ushort_t;
using bf16x8 = __attribute__((ext_vector_type(8))) short;
using f32x16 = __attribute__((ext_vector_type(16))) float;

#define KT 27
#define NV 65536

__device__ inline unsigned short f2bf(float f) {
  unsigned int u = __builtin_bit_cast(unsigned int, f);
  u += 0x7fffu + ((u >> 16) & 1u);
  return (unsigned short)(u >> 16);
}

// W[k][c][d] fp32 -> per-lane-swizzled MFMA B fragments (bf16):
// Wf[(k*8 + ks*2 + ct)*512 + l*8 + j] = bf16(W[k][ks*16 + (l>>5)*8 + j][ct*32 + (l&31)])
// so a B-frag load is wave-uniform base + lane*16B: perfectly coalesced, 1KB contiguous.
__global__ __launch_bounds__(256) void k_wprep(const float* __restrict__ W1,
                                               const float* __restrict__ W2,
                                               ushort_t* __restrict__ Wf1,
                                               ushort_t* __restrict__ Wf2) {
  int e = blockIdx.x * 256 + threadIdx.x;  // 2 * 221184 total
  const float* W = W1; ushort_t* Wf = Wf1;
  if (e >= 221184) { e -= 221184; W = W2; Wf = Wf2; }
  int j = e & 7, l = (e >> 3) & 63, u = (e >> 9) & 7, k = e >> 12;
  int ks = u >> 1, ct = u & 1;
  int c = ks * 16 + (l >> 5) * 8 + j;
  int d = ct * 32 + (l & 31);
  Wf[e] = f2bf(W[(k << 12) + (c << 6) + d]);
}

// Gather-GEMM conv, 32x32x16 MFMA.
// block = 256 thr = 4 waves, owns 128 voxels; wave w owns voxels w*32..+31, all 64 out ch.
// A staged in LDS as As[buf][c8][vox][8] (c8 = 8-channel chunk) -> all LDS ops are
// contiguous-lane b128 (structural-minimum bank phases). B frags register-direct from
// pre-swizzled Wf (L1-resident). One barrier per tap, A double-buffered, B 2-tap pipelined.
// BN=true: source is fp32 pre-BN activations; BN+ReLU applied inline during staging.
template<bool BN>
__global__ __launch_bounds__(256, 2) void k_conv(const float* __restrict__ src,   // [N][64] fp32
                                                 const int* __restrict__ nbr,     // [N][27]
                                                 const ushort_t* __restrict__ Wf, // swizzled frags
                                                 float* __restrict__ hout,        // [N][64] fp32
                                                 const float* __restrict__ gsum_in,
                                                 const float* __restrict__ gsq_in,
                                                 const float* __restrict__ gamma,
                                                 const float* __restrict__ beta,
                                                 float* __restrict__ gsum,
                                                 float* __restrict__ gsq) {
  __shared__ ushort_t As[2][8 * 128 * 8];   // 32 KB
  __shared__ int nb_l[128 * KT];            // 13.8 KB
  __shared__ float red[2][4][64];           // 2 KB

  const int t = threadIdx.x;
  const int base = blockIdx.x * 128;
  const int c8 = t & 7;                     // this thread's 8-channel staging chunk (fixed)

  // BN params for this thread's staging channels (computed once, redundantly per thread)
  float psc[8], psh[8];
  if (BN) {
#pragma unroll
    for (int n = 0; n < 8; ++n) {
      int c = c8 * 8 + n;
      float mean = gsum_in[c] * (1.f / NV);
      float var  = gsq_in[c] * (1.f / NV) - mean * mean;
      float rs = rsqrtf(var + 1e-5f);
      psc[n] = gamma[c] * rs;
      psh[n] = beta[c] - mean * psc[n];
    }
  }

  for (int e = t; e < 128 * KT; e += 256) nb_l[e] = nbr[base * KT + e];

  const int lane = t & 63;
  const int w = t >> 6;
  const int hh = lane >> 5;        // half-wave
  const int r31 = lane & 31;
  const int wvox = w * 32;

  f32x16 acc0 = {0,0,0,0,0,0,0,0,0,0,0,0,0,0,0,0};
  f32x16 acc1 = {0,0,0,0,0,0,0,0,0,0,0,0,0,0,0,0};

  // stage tap k's gathered A tile (128 vox x 64 ch, bf16) into As[buf]
  auto stage = [&](int k, int buf) {
    ushort_t* asb = &As[buf][0];
#pragma unroll
    for (int i = 0; i < 4; ++i) {
      int vox = (t >> 3) + i * 32;
      int idx = nb_l[vox * KT + k];
      bf16x8 ov = {0, 0, 0, 0, 0, 0, 0, 0};
      if (idx >= 0) {
        const float* p = src + idx * 64 + c8 * 8;
        float4 v0 = *(const float4*)p;
        float4 v1 = *(const float4*)(p + 4);
        float f[8] = {v0.x, v0.y, v0.z, v0.w, v1.x, v1.y, v1.z, v1.w};
#pragma unroll
        for (int n = 0; n < 8; ++n) {
          float xv = f[n];
          if (BN) xv = fmaxf(0.f, xv * psc[n] + psh[n]);
          ov[n] = (short)f2bf(xv);
        }
      }
      *(bf16x8*)(asb + c8 * 1024 + vox * 8) = ov;  // 16B-aligned, contiguous-lane b128
    }
  };

  // load tap k's 8 B-fragments (ks x ct) register-direct from Wf
  auto loadB = [&](int k, bf16x8* b) {
    const ushort_t* p = Wf + (k * 8) * 512 + lane * 8;
#pragma unroll
    for (int u = 0; u < 8; ++u) b[u] = *(const bf16x8*)(p + u * 512);
  };

  // 8 MFMAs for one tap from As[buf] + B regs
  auto compute = [&](int buf, const bf16x8* b) {
    const ushort_t* ar = &As[buf][0] + (wvox + r31) * 8;
#pragma unroll
    for (int ks = 0; ks < 4; ++ks) {
      bf16x8 af = *(const bf16x8*)(ar + (ks * 2 + hh) * 1024);
      acc0 = __builtin_amdgcn_mfma_f32_32x32x16_bf16(af, b[ks * 2 + 0], acc0, 0, 0, 0);
      acc1 = __builtin_amdgcn_mfma_f32_32x32x16_bf16(af, b[ks * 2 + 1], acc1, 0, 0, 0);
    }
  };

  bf16x8 bA[8], bB[8];

  __syncthreads();                 // nb_l ready
  loadB(0, bA);
  stage(0, 0);
  __syncthreads();                 // As[0] ready

  // taps: even -> As[0], odd -> As[1] (compile-time buf indices for alias analysis)
  for (int it = 0; it < 13; ++it) {
    const int kk = it * 2;
    stage(kk + 1, 1);
    loadB(kk + 1, bB);
    compute(0, bA);                // tap kk
    __syncthreads();
    stage(kk + 2, 0);
    loadB(kk + 2, bA);
    compute(1, bB);                // tap kk+1
    __syncthreads();
  }
  compute(0, bA);                  // tap 26

  // epilogue: store + fused per-channel stats
  // C/D (32x32): col = lane&31, row = (reg&3) + 8*(reg>>2) + 4*(lane>>5)
  const int orow0 = base + wvox + (hh << 2);
  float s0 = 0.f, q0 = 0.f, s1 = 0.f, q1 = 0.f;
#pragma unroll
  for (int reg = 0; reg < 16; ++reg) {
    int row = orow0 + (reg & 3) + 8 * (reg >> 2);
    float v0 = acc0[reg], v1 = acc1[reg];
    hout[row * 64 + r31] = v0;
    hout[row * 64 + 32 + r31] = v1;
    s0 += v0; q0 += v0 * v0;
    s1 += v1; q1 += v1 * v1;
  }
  s0 += __shfl_xor(s0, 32, 64); q0 += __shfl_xor(q0, 32, 64);
  s1 += __shfl_xor(s1, 32, 64); q1 += __shfl_xor(q1, 32, 64);
  if (hh == 0) {
    red[0][w][r31] = s0; red[0][w][32 + r31] = s1;
    red[1][w][r31] = q0; red[1][w][32 + r31] = q1;
  }
  __syncthreads();
  if (t < 128) {
    int which = t >> 6, c = t & 63;
    float v = red[which][0][c] + red[which][1][c] + red[which][2][c] + red[which][3][c];
    atomicAdd((which ? gsq : gsum) + c, v);
  }
}

// BN2 (inline params) + residual + ReLU, fp32 out
__global__ __launch_bounds__(256) void k_final(const float* __restrict__ h,
                                               const float* __restrict__ x,
                                               const float* __restrict__ gsum,
                                               const float* __restrict__ gsq,
                                               const float* __restrict__ gamma,
                                               const float* __restrict__ beta,
                                               float* __restrict__ out) {
  __shared__ float sc[64], sh[64];
  int t = threadIdx.x;
  if (t < 64) {
    float mean = gsum[t] * (1.f / NV);
    float var = gsq[t] * (1.f / NV) - mean * mean;
    float rs = rsqrtf(var + 1e-5f);
    float s = gamma[t] * rs;
    sc[t] = s;
    sh[t] = beta[t] - mean * s;
  }
  __syncthreads();
  int i = blockIdx.x * 256 + t;
  int c0 = (i << 2) & 63;
  float4 v = ((const float4*)h)[i];
  float4 xv = ((const float4*)x)[i];
  float4 o;
  o.x = fmaxf(0.f, v.x * sc[c0]     + sh[c0]     + xv.x);
  o.y = fmaxf(0.f, v.y * sc[c0 + 1] + sh[c0 + 1] + xv.y);
  o.z = fmaxf(0.f, v.z * sc[c0 + 2] + sh[c0 + 2] + xv.z);
  o.w = fmaxf(0.f, v.w * sc[c0 + 3] + sh[c0 + 3] + xv.w);
  ((float4*)out)[i] = o;
}

extern "C" void kernel_launch(void* const* d_in, const int* in_sizes, int n_in,
                              void* d_out, int out_size, void* d_ws, size_t ws_size,
                              hipStream_t stream) {
  const float* x   = (const float*)d_in[0];
  const int*   nbr = (const int*)d_in[1];
  const float* W1  = (const float*)d_in[2];
  const float* g1  = (const float*)d_in[3];
  const float* b1  = (const float*)d_in[4];
  const float* W2  = (const float*)d_in[5];
  const float* g2  = (const float*)d_in[6];
  const float* b2  = (const float*)d_in[7];
  float* out = (float*)d_out;
  char* ws = (char*)d_ws;

  // workspace layout (bytes, 256-aligned), total ~34.4 MB
  ushort_t* Wf1   = (ushort_t*)(ws);               // 442,368
  ushort_t* Wf2   = (ushort_t*)(ws + 442368);      // 442,368
  float*    h1raw = (float*)(ws + 884736);         // 16,777,216
  float*    h2raw = (float*)(ws + 17661952);       // 16,777,216
  float*    statsp = (float*)(ws + 34439168);      // 256 floats
  float *gsum1 = statsp, *gsq1 = statsp + 64, *gsum2 = statsp + 128, *gsq2 = statsp + 192;

  hipMemsetAsync(statsp, 0, 256 * sizeof(float), stream);

  k_wprep<<<1728, 256, 0, stream>>>(W1, W2, Wf1, Wf2);

  // conv1: gathers fp32 x, converts to bf16 inline during staging
  k_conv<false><<<512, 256, 0, stream>>>(x, nbr, Wf1, h1raw,
                                         nullptr, nullptr, nullptr, nullptr, gsum1, gsq1);
  // conv2: gathers fp32 h1, applies BN1+ReLU inline during staging (dispatch = grid sync)
  k_conv<true><<<512, 256, 0, stream>>>(h1raw, nbr, Wf2, h2raw,
                                        gsum1, gsq1, g1, b1, gsum2, gsq2);

  k_final<<<4096, 256, 0, stream>>>(h2raw, x, gsum2, gsq2, g2, b2, out);
}

// Round 4
// 215.386 us; speedup vs baseline: 1.5287x; 1.0861x over previous
//
#include <hip/hip_runtime.h>

typedef unsigned short ushort_t;
using bf16x8 = __attribute__((ext_vector_type(8))) short;
using f32x16 = __attribute__((ext_vector_type(16))) float;

#define KT 27
#define NV 65536

__device__ inline unsigned short f2bf(float f) {
  unsigned int u = __builtin_bit_cast(unsigned int, f);
  u += 0x7fffu + ((u >> 16) & 1u);
  return (unsigned short)(u >> 16);
}
__device__ inline float b2f(ushort_t u) {
  unsigned int x = ((unsigned int)u) << 16;
  return __builtin_bit_cast(float, x);
}

// merged prep: x fp32->bf16 (blocks 0..4095); W1,W2 [k][c][d] -> per-lane MFMA B frags (blocks 4096..5823)
// Wf[(k*8 + ks*2 + ct)*512 + l*8 + j] = bf16(W[k][ks*16 + (l>>5)*8 + j][ct*32 + (l&31)])
__global__ __launch_bounds__(256) void k_prep(const float* __restrict__ x,
                                              const float* __restrict__ W1,
                                              const float* __restrict__ W2,
                                              ushort_t* __restrict__ xb,
                                              ushort_t* __restrict__ Wf1,
                                              ushort_t* __restrict__ Wf2) {
  int b = blockIdx.x;
  int t = threadIdx.x;
  if (b < 4096) {
    int i = b * 256 + t;  // float4 index
    float4 v = ((const float4*)x)[i];
    ushort4 o;
    o.x = f2bf(v.x); o.y = f2bf(v.y); o.z = f2bf(v.z); o.w = f2bf(v.w);
    ((ushort4*)xb)[i] = o;
  } else {
    int e = (b - 4096) * 256 + t;  // < 442368
    const float* W = W1; ushort_t* Wf = Wf1;
    if (e >= 221184) { e -= 221184; W = W2; Wf = Wf2; }
    int j = e & 7, l = (e >> 3) & 63, u = (e >> 9) & 7, k = e >> 12;
    int ks = u >> 1, ct = u & 1;
    int c = ks * 16 + (l >> 5) * 8 + j;
    int d = ct * 32 + (l & 31);
    Wf[e] = f2bf(W[(k << 12) + (c << 6) + d]);
  }
}

// Gather-GEMM conv, 32x32x16 MFMA. block = 256 thr = 4 waves, 128 voxels.
// A tile in LDS, row-major [vox][64ch] with XOR-swizzled 16B chunks:
//   chunk c of row v lives at v*64 + (c ^ (v&7))*8 (ushort offsets)
//   -> staging writes are linear-in-thread (conflict-free), frag reads spread all 8 bank groups.
// B frags register-direct from pre-swizzled Wf (L1-resident). bf16 gather = pure copy.
// OBF16: write hout as bf16 (conv1) vs fp32 (conv2). Stats always fp32-exact from acc.
template<bool OBF16>
__global__ __launch_bounds__(256, 3) void k_conv(const ushort_t* __restrict__ src,  // [N][64] bf16
                                                 const int* __restrict__ nbr,       // [N][27]
                                                 const ushort_t* __restrict__ Wf,
                                                 void* __restrict__ houtv,          // [N][64]
                                                 float* __restrict__ gsum,
                                                 float* __restrict__ gsq) {
  __shared__ alignas(16) ushort_t As[2][8192];  // 2 x 16 KB
  __shared__ int nb_l[128 * KT];                // 13.8 KB
  __shared__ float red[2][4][64];               // 2 KB

  const int t = threadIdx.x;
  const int base = blockIdx.x * 128;

  for (int e = t; e < 128 * KT; e += 256) nb_l[e] = nbr[base * KT + e];

  const int lane = t & 63;
  const int w = t >> 6;
  const int hh = lane >> 5;
  const int r31 = lane & 31;
  const int wvox = w * 32;

  const int srow = t >> 3;                       // staging row (0..31), +32*i
  const int co = (t & 7) * 8;                    // source channel offset (ushorts)
  const int d0 = srow * 64 + (((t & 7) ^ (srow & 7)) * 8);  // swizzled LDS dest (ushorts)

  f32x16 acc0 = {0,0,0,0,0,0,0,0,0,0,0,0,0,0,0,0};
  f32x16 acc1 = {0,0,0,0,0,0,0,0,0,0,0,0,0,0,0,0};

  auto stage = [&](int k, int buf) {
#pragma unroll
    for (int i = 0; i < 4; ++i) {
      int vox = srow + i * 32;
      int idx = nb_l[vox * KT + k];
      uint4 val = {0u, 0u, 0u, 0u};
      if (idx >= 0) val = *(const uint4*)(src + idx * 64 + co);
      *(uint4*)(&As[buf][d0 + i * 2048]) = val;
    }
  };

  auto loadB = [&](int k, bf16x8* b) {
    const ushort_t* p = Wf + k * 4096 + lane * 8;
#pragma unroll
    for (int u = 0; u < 8; ++u) b[u] = *(const bf16x8*)(p + u * 512);
  };

  auto compute = [&](int buf, const bf16x8* b) {
    const ushort_t* ar = &As[buf][(wvox + r31) * 64];
    const int s7 = r31 & 7;
#pragma unroll
    for (int ks = 0; ks < 4; ++ks) {
      bf16x8 af = *(const bf16x8*)(ar + ((ks * 2 + hh) ^ s7) * 8);
      acc0 = __builtin_amdgcn_mfma_f32_32x32x16_bf16(af, b[ks * 2 + 0], acc0, 0, 0, 0);
      acc1 = __builtin_amdgcn_mfma_f32_32x32x16_bf16(af, b[ks * 2 + 1], acc1, 0, 0, 0);
    }
  };

  bf16x8 bA[8], bB[8];

  __syncthreads();                 // nb_l ready
  loadB(0, bA);
  stage(0, 0);
  __syncthreads();                 // As[0] ready

  for (int it = 0; it < 13; ++it) {
    const int kk = it * 2;
    stage(kk + 1, 1);
    loadB(kk + 1, bB);
    compute(0, bA);                // tap kk
    __syncthreads();
    stage(kk + 2, 0);
    loadB(kk + 2, bA);
    compute(1, bB);                // tap kk+1
    __syncthreads();
  }
  compute(0, bA);                  // tap 26

  // epilogue: store h + fused per-channel stats
  // C/D (32x32): col = lane&31, row = (reg&3) + 8*(reg>>2) + 4*(lane>>5)
  const int orow0 = base + wvox + (hh << 2);
  float s0 = 0.f, q0 = 0.f, s1 = 0.f, q1 = 0.f;
#pragma unroll
  for (int reg = 0; reg < 16; ++reg) {
    int row = orow0 + (reg & 3) + 8 * (reg >> 2);
    float v0 = acc0[reg], v1 = acc1[reg];
    if (OBF16) {
      ushort_t* ho = (ushort_t*)houtv;
      ho[row * 64 + r31] = f2bf(v0);
      ho[row * 64 + 32 + r31] = f2bf(v1);
    } else {
      float* ho = (float*)houtv;
      ho[row * 64 + r31] = v0;
      ho[row * 64 + 32 + r31] = v1;
    }
    s0 += v0; q0 += v0 * v0;
    s1 += v1; q1 += v1 * v1;
  }
  s0 += __shfl_xor(s0, 32, 64); q0 += __shfl_xor(q0, 32, 64);
  s1 += __shfl_xor(s1, 32, 64); q1 += __shfl_xor(q1, 32, 64);
  if (hh == 0) {
    red[0][w][r31] = s0; red[0][w][32 + r31] = s1;
    red[1][w][r31] = q0; red[1][w][32 + r31] = q1;
  }
  __syncthreads();
  if (t < 128) {
    int which = t >> 6, c = t & 63;
    float v = red[which][0][c] + red[which][1][c] + red[which][2][c] + red[which][3][c];
    atomicAdd((which ? gsq : gsum) + c, v);
  }
}

// BN1 (inline params from raw stats) + ReLU on bf16 h1, writes bf16 for conv2's gather
__global__ __launch_bounds__(256) void k_bn_relu(const ushort_t* __restrict__ h,
                                                 const float* __restrict__ gsum,
                                                 const float* __restrict__ gsq,
                                                 const float* __restrict__ gamma,
                                                 const float* __restrict__ beta,
                                                 ushort_t* __restrict__ ob) {
  __shared__ float sc[64], sh[64];
  int t = threadIdx.x;
  if (t < 64) {
    float mean = gsum[t] * (1.f / NV);
    float var = gsq[t] * (1.f / NV) - mean * mean;
    float rs = rsqrtf(var + 1e-5f);
    float s = gamma[t] * rs;
    sc[t] = s;
    sh[t] = beta[t] - mean * s;
  }
  __syncthreads();
  int i = blockIdx.x * 256 + t;    // uint4 index = 8 bf16
  int c0 = (i & 7) * 8;
  uint4 v = ((const uint4*)h)[i];
  const ushort_t* pu = (const ushort_t*)&v;
  uint4 o;
  ushort_t* po = (ushort_t*)&o;
#pragma unroll
  for (int n = 0; n < 8; ++n)
    po[n] = f2bf(fmaxf(0.f, b2f(pu[n]) * sc[c0 + n] + sh[c0 + n]));
  ((uint4*)ob)[i] = o;
}

// BN2 (inline params) + residual + ReLU, fp32 out
__global__ __launch_bounds__(256) void k_final(const float* __restrict__ h,
                                               const float* __restrict__ x,
                                               const float* __restrict__ gsum,
                                               const float* __restrict__ gsq,
                                               const float* __restrict__ gamma,
                                               const float* __restrict__ beta,
                                               float* __restrict__ out) {
  __shared__ float sc[64], sh[64];
  int t = threadIdx.x;
  if (t < 64) {
    float mean = gsum[t] * (1.f / NV);
    float var = gsq[t] * (1.f / NV) - mean * mean;
    float rs = rsqrtf(var + 1e-5f);
    float s = gamma[t] * rs;
    sc[t] = s;
    sh[t] = beta[t] - mean * s;
  }
  __syncthreads();
  int i = blockIdx.x * 256 + t;
  int c0 = (i << 2) & 63;
  float4 v = ((const float4*)h)[i];
  float4 xv = ((const float4*)x)[i];
  float4 o;
  o.x = fmaxf(0.f, v.x * sc[c0]     + sh[c0]     + xv.x);
  o.y = fmaxf(0.f, v.y * sc[c0 + 1] + sh[c0 + 1] + xv.y);
  o.z = fmaxf(0.f, v.z * sc[c0 + 2] + sh[c0 + 2] + xv.z);
  o.w = fmaxf(0.f, v.w * sc[c0 + 3] + sh[c0 + 3] + xv.w);
  ((float4*)out)[i] = o;
}

extern "C" void kernel_launch(void* const* d_in, const int* in_sizes, int n_in,
                              void* d_out, int out_size, void* d_ws, size_t ws_size,
                              hipStream_t stream) {
  const float* x   = (const float*)d_in[0];
  const int*   nbr = (const int*)d_in[1];
  const float* W1  = (const float*)d_in[2];
  const float* g1  = (const float*)d_in[3];
  const float* b1  = (const float*)d_in[4];
  const float* W2  = (const float*)d_in[5];
  const float* g2  = (const float*)d_in[6];
  const float* b2  = (const float*)d_in[7];
  float* out = (float*)d_out;
  char* ws = (char*)d_ws;

  // workspace layout (bytes, 256-aligned), total ~42.8 MB
  ushort_t* xb     = (ushort_t*)(ws);               // 8,388,608
  ushort_t* h1pre  = (ushort_t*)(ws + 8388608);     // 8,388,608 (bf16, pre-BN)
  ushort_t* h1post = (ushort_t*)(ws + 16777216);    // 8,388,608 (bf16, post-BN+ReLU)
  ushort_t* Wf1    = (ushort_t*)(ws + 25165824);    // 442,368
  ushort_t* Wf2    = (ushort_t*)(ws + 25608192);    // 442,368
  float*    h2raw  = (float*)(ws + 26050560);       // 16,777,216
  float*    statsp = (float*)(ws + 42827776);       // 256 floats
  float *gsum1 = statsp, *gsq1 = statsp + 64, *gsum2 = statsp + 128, *gsq2 = statsp + 192;

  hipMemsetAsync(statsp, 0, 256 * sizeof(float), stream);

  k_prep<<<5824, 256, 0, stream>>>(x, W1, W2, xb, Wf1, Wf2);

  k_conv<true><<<512, 256, 0, stream>>>(xb, nbr, Wf1, (void*)h1pre, gsum1, gsq1);
  k_bn_relu<<<2048, 256, 0, stream>>>(h1pre, gsum1, gsq1, g1, b1, h1post);
  k_conv<false><<<512, 256, 0, stream>>>(h1post, nbr, Wf2, (void*)h2raw, gsum2, gsq2);

  k_final<<<4096, 256, 0, stream>>>(h2raw, x, gsum2, gsq2, g2, b2, out);
}

// Round 5
// 171.546 us; speedup vs baseline: 1.9194x; 1.2556x over previous
//
#include <hip/hip_runtime.h>

typedef unsigned short ushort_t;
using bf16x8 = __attribute__((ext_vector_type(8))) short;
using f32x16 = __attribute__((ext_vector_type(16))) float;

#define KT 27
#define NV 65536

__device__ inline unsigned short f2bf(float f) {
  unsigned int u = __builtin_bit_cast(unsigned int, f);
  u += 0x7fffu + ((u >> 16) & 1u);
  return (unsigned short)(u >> 16);
}
__device__ inline float b2f(ushort_t u) {
  unsigned int x = ((unsigned int)u) << 16;
  return __builtin_bit_cast(float, x);
}

// merged prep: statsp zero (block 0), x fp32->bf16 (blocks 0..4095),
// W1,W2 [k][c][d] -> per-lane MFMA B frags (blocks 4096..5823)
// Wf[(k*8 + ks*2 + ct)*512 + l*8 + j] = bf16(W[k][ks*16 + (l>>5)*8 + j][ct*32 + (l&31)])
__global__ __launch_bounds__(256) void k_prep(const float* __restrict__ x,
                                              const float* __restrict__ W1,
                                              const float* __restrict__ W2,
                                              ushort_t* __restrict__ xb,
                                              ushort_t* __restrict__ Wf1,
                                              ushort_t* __restrict__ Wf2,
                                              float* __restrict__ statsp) {
  int b = blockIdx.x;
  int t = threadIdx.x;
  if (b == 0) statsp[t] = 0.f;     // 256 floats; convs run after this dispatch
  if (b < 4096) {
    int i = b * 256 + t;  // float4 index
    float4 v = ((const float4*)x)[i];
    ushort4 o;
    o.x = f2bf(v.x); o.y = f2bf(v.y); o.z = f2bf(v.z); o.w = f2bf(v.w);
    ((ushort4*)xb)[i] = o;
  } else {
    int e = (b - 4096) * 256 + t;  // < 442368
    const float* W = W1; ushort_t* Wf = Wf1;
    if (e >= 221184) { e -= 221184; W = W2; Wf = Wf2; }
    int j = e & 7, l = (e >> 3) & 63, u = (e >> 9) & 7, k = e >> 12;
    int ks = u >> 1, ct = u & 1;
    int c = ks * 16 + (l >> 5) * 8 + j;
    int d = ct * 32 + (l & 31);
    Wf[e] = f2bf(W[(k << 12) + (c << 6) + d]);
  }
}

// Gather-GEMM conv, 32x32x16 MFMA, BARRIER-FREE K-loop.
// block = 256 thr = 4 fully independent waves; wave w owns voxels wbase..wbase+31.
// Wave-local LDS A tile (own region, double-buffered): same-wave DS in-order =>
// no __syncthreads, compiler emits fine-grained vmcnt/lgkmcnt only.
// Pipeline: ldA(k+2)->regs | ldB(k+1)->regs | wrLDS(k+1) | compute(k).
// A LDS layout: row-major [row][64ch], 16B chunk index XOR-swizzled by row&7
// (staging writes linear-in-thread, frag reads spread across all 8 bank groups).
// B frags register-direct from pre-swizzled Wf (L1/L2-resident).
template<bool OBF16>
__global__ __launch_bounds__(256, 2) void k_conv(const ushort_t* __restrict__ src,  // [N][64] bf16
                                                 const int* __restrict__ nbr,       // [N][27]
                                                 const ushort_t* __restrict__ Wf,
                                                 void* __restrict__ houtv,          // [N][64]
                                                 float* __restrict__ gsum,
                                                 float* __restrict__ gsq) {
  __shared__ alignas(16) ushort_t As[4][2][2048];  // per-wave double-buffered 32x64 tile, 32 KB
  __shared__ int nb_l[4][32 * KT];                 // per-wave rulebook rows, 13.8 KB
  __shared__ float red[2][4][64];                  // stats reduce, 2 KB

  const int t = threadIdx.x;
  const int lane = t & 63;
  const int w = t >> 6;
  const int hh = lane >> 5;
  const int r31 = lane & 31;
  const int wbase = blockIdx.x * 128 + w * 32;

  int* nbw = &nb_l[w][0];
  {
    const int* nbg = nbr + wbase * KT;
    for (int e = lane; e < 32 * KT; e += 64) nbw[e] = nbg[e];  // wave-local: no barrier
  }

  const int srow0 = lane >> 3;       // staging row (+8*i)
  const int sch = (lane & 7) * 8;    // channel offset (ushorts)

  f32x16 acc0 = {0,0,0,0,0,0,0,0,0,0,0,0,0,0,0,0};
  f32x16 acc1 = {0,0,0,0,0,0,0,0,0,0,0,0,0,0,0,0};

  uint4 rA[2][4];
  bf16x8 bB[2][8];

  auto ldA = [&](int k, uint4* r) {
#pragma unroll
    for (int i = 0; i < 4; ++i) {
      int row = srow0 + i * 8;
      int idx = nbw[row * KT + k];
      uint4 v = {0u, 0u, 0u, 0u};
      if (idx >= 0) v = *(const uint4*)(src + idx * 64 + sch);
      r[i] = v;
    }
  };
  auto wrA = [&](int buf, const uint4* r) {
#pragma unroll
    for (int i = 0; i < 4; ++i) {
      int row = srow0 + i * 8;
      *(uint4*)(&As[w][buf][row * 64 + (((lane & 7) ^ (row & 7)) * 8)]) = r[i];
    }
  };
  auto ldB = [&](int k, bf16x8* b) {
    const ushort_t* p = Wf + k * 4096 + lane * 8;
#pragma unroll
    for (int u = 0; u < 8; ++u) b[u] = *(const bf16x8*)(p + u * 512);
  };
  auto compute = [&](int buf, const bf16x8* b) {
    const ushort_t* ar = &As[w][buf][r31 * 64];
    const int s7 = r31 & 7;
#pragma unroll
    for (int ks = 0; ks < 4; ++ks) {
      bf16x8 af = *(const bf16x8*)(ar + (((ks * 2 + hh) ^ s7) * 8));
      acc0 = __builtin_amdgcn_mfma_f32_32x32x16_bf16(af, b[ks * 2 + 0], acc0, 0, 0, 0);
      acc1 = __builtin_amdgcn_mfma_f32_32x32x16_bf16(af, b[ks * 2 + 1], acc1, 0, 0, 0);
    }
  };

  // prologue: buf0 <- tap0, rA[1] <- tap1, bB[0] <- B(0)
  ldA(0, rA[0]);
  ldA(1, rA[1]);
  ldB(0, bB[0]);
  wrA(0, rA[0]);

  // invariant at iter k: buf(k&1)=tap k, rA[(k+1)&1]=tap k+1 (regs), bB[k&1]=B(k)
#pragma unroll
  for (int k = 0; k < KT; ++k) {
    const int cur = k & 1, nxt = cur ^ 1;
    const int k2 = (k + 2 < KT) ? k + 2 : KT - 1;   // tail clamps (redundant, harmless)
    const int k1 = (k + 1 < KT) ? k + 1 : KT - 1;
    ldA(k2, rA[cur]);        // 2-iteration latency slack before its wrA
    ldB(k1, bB[nxt]);        // 1-iteration slack before its compute
    wrA(nxt, rA[nxt]);       // tap k+1 -> LDS (vmcnt waits only these 4 loads)
    compute(cur, bB[cur]);   // tap k (same-wave DS in-order; lgkmcnt only)
  }

  // epilogue: store h + fused per-channel stats
  // C/D (32x32): col = lane&31, row = (reg&3) + 8*(reg>>2) + 4*(lane>>5)
  const int orow0 = wbase + (hh << 2);
  float s0 = 0.f, q0 = 0.f, s1 = 0.f, q1 = 0.f;
#pragma unroll
  for (int reg = 0; reg < 16; ++reg) {
    int row = orow0 + (reg & 3) + 8 * (reg >> 2);
    float v0 = acc0[reg], v1 = acc1[reg];
    if (OBF16) {
      ushort_t* ho = (ushort_t*)houtv;
      ho[row * 64 + r31] = f2bf(v0);
      ho[row * 64 + 32 + r31] = f2bf(v1);
    } else {
      float* ho = (float*)houtv;
      ho[row * 64 + r31] = v0;
      ho[row * 64 + 32 + r31] = v1;
    }
    s0 += v0; q0 += v0 * v0;
    s1 += v1; q1 += v1 * v1;
  }
  s0 += __shfl_xor(s0, 32, 64); q0 += __shfl_xor(q0, 32, 64);
  s1 += __shfl_xor(s1, 32, 64); q1 += __shfl_xor(q1, 32, 64);
  if (hh == 0) {
    red[0][w][r31] = s0; red[0][w][32 + r31] = s1;
    red[1][w][r31] = q0; red[1][w][32 + r31] = q1;
  }
  __syncthreads();   // only barrier in the kernel
  if (t < 128) {
    int which = t >> 6, c = t & 63;
    float v = red[which][0][c] + red[which][1][c] + red[which][2][c] + red[which][3][c];
    atomicAdd((which ? gsq : gsum) + c, v);
  }
}

// BN1 (inline params from raw stats) + ReLU on bf16 h1, writes bf16 for conv2's gather
__global__ __launch_bounds__(256) void k_bn_relu(const ushort_t* __restrict__ h,
                                                 const float* __restrict__ gsum,
                                                 const float* __restrict__ gsq,
                                                 const float* __restrict__ gamma,
                                                 const float* __restrict__ beta,
                                                 ushort_t* __restrict__ ob) {
  __shared__ float sc[64], sh[64];
  int t = threadIdx.x;
  if (t < 64) {
    float mean = gsum[t] * (1.f / NV);
    float var = gsq[t] * (1.f / NV) - mean * mean;
    float rs = rsqrtf(var + 1e-5f);
    float s = gamma[t] * rs;
    sc[t] = s;
    sh[t] = beta[t] - mean * s;
  }
  __syncthreads();
  int i = blockIdx.x * 256 + t;    // uint4 index = 8 bf16
  int c0 = (i & 7) * 8;
  uint4 v = ((const uint4*)h)[i];
  const ushort_t* pu = (const ushort_t*)&v;
  uint4 o;
  ushort_t* po = (ushort_t*)&o;
#pragma unroll
  for (int n = 0; n < 8; ++n)
    po[n] = f2bf(fmaxf(0.f, b2f(pu[n]) * sc[c0 + n] + sh[c0 + n]));
  ((uint4*)ob)[i] = o;
}

// BN2 (inline params) + residual + ReLU, fp32 out
__global__ __launch_bounds__(256) void k_final(const float* __restrict__ h,
                                               const float* __restrict__ x,
                                               const float* __restrict__ gsum,
                                               const float* __restrict__ gsq,
                                               const float* __restrict__ gamma,
                                               const float* __restrict__ beta,
                                               float* __restrict__ out) {
  __shared__ float sc[64], sh[64];
  int t = threadIdx.x;
  if (t < 64) {
    float mean = gsum[t] * (1.f / NV);
    float var = gsq[t] * (1.f / NV) - mean * mean;
    float rs = rsqrtf(var + 1e-5f);
    float s = gamma[t] * rs;
    sc[t] = s;
    sh[t] = beta[t] - mean * s;
  }
  __syncthreads();
  int i = blockIdx.x * 256 + t;
  int c0 = (i << 2) & 63;
  float4 v = ((const float4*)h)[i];
  float4 xv = ((const float4*)x)[i];
  float4 o;
  o.x = fmaxf(0.f, v.x * sc[c0]     + sh[c0]     + xv.x);
  o.y = fmaxf(0.f, v.y * sc[c0 + 1] + sh[c0 + 1] + xv.y);
  o.z = fmaxf(0.f, v.z * sc[c0 + 2] + sh[c0 + 2] + xv.z);
  o.w = fmaxf(0.f, v.w * sc[c0 + 3] + sh[c0 + 3] + xv.w);
  ((float4*)out)[i] = o;
}

extern "C" void kernel_launch(void* const* d_in, const int* in_sizes, int n_in,
                              void* d_out, int out_size, void* d_ws, size_t ws_size,
                              hipStream_t stream) {
  const float* x   = (const float*)d_in[0];
  const int*   nbr = (const int*)d_in[1];
  const float* W1  = (const float*)d_in[2];
  const float* g1  = (const float*)d_in[3];
  const float* b1  = (const float*)d_in[4];
  const float* W2  = (const float*)d_in[5];
  const float* g2  = (const float*)d_in[6];
  const float* b2  = (const float*)d_in[7];
  float* out = (float*)d_out;
  char* ws = (char*)d_ws;

  // workspace layout (bytes, 256-aligned), total ~42.8 MB
  ushort_t* xb     = (ushort_t*)(ws);               // 8,388,608
  ushort_t* h1pre  = (ushort_t*)(ws + 8388608);     // 8,388,608 (bf16, pre-BN)
  ushort_t* h1post = (ushort_t*)(ws + 16777216);    // 8,388,608 (bf16, post-BN+ReLU)
  ushort_t* Wf1    = (ushort_t*)(ws + 25165824);    // 442,368
  ushort_t* Wf2    = (ushort_t*)(ws + 25608192);    // 442,368
  float*    h2raw  = (float*)(ws + 26050560);       // 16,777,216
  float*    statsp = (float*)(ws + 42827776);       // 256 floats
  float *gsum1 = statsp, *gsq1 = statsp + 64, *gsum2 = statsp + 128, *gsq2 = statsp + 192;

  k_prep<<<5824, 256, 0, stream>>>(x, W1, W2, xb, Wf1, Wf2, statsp);

  k_conv<true><<<512, 256, 0, stream>>>(xb, nbr, Wf1, (void*)h1pre, gsum1, gsq1);
  k_bn_relu<<<2048, 256, 0, stream>>>(h1pre, gsum1, gsq1, g1, b1, h1post);
  k_conv<false><<<512, 256, 0, stream>>>(h1post, nbr, Wf2, (void*)h2raw, gsum2, gsq2);

  k_final<<<4096, 256, 0, stream>>>(h2raw, x, gsum2, gsq2, g2, b2, out);
}